// Round 4
// baseline (144.450 us; speedup 1.0000x reference)
//
#include <hip/hip_runtime.h>
#include <math.h>

#define N_POSE   1024
#define M_TRAIN  10000
#define NJOINT   21
#define TPB      64       // one wave per block
#define KNEIGH   5
#define CLIPV    (1.0f - 1e-7f)
#define PI_F     3.14159265358979f
#define BIGF     1e30f
#define JH       11       // joints per half-lane (h=1: 10 real + 1 dummy)

// A&S 4.4.45 poly (abs err ~1.8e-4) with raw v_sqrt_f32 (no ocml fixup code)
__device__ __forceinline__ float acos_fast(float d) {
    float a = fminf(fabsf(d), CLIPV);           // clamp folded into abs+min
    float p = fmaf(a, -0.0187293f, 0.0742610f);
    p = fmaf(a, p, -0.2121144f);
    p = fmaf(a, p, 1.5707288f);
    float r = __builtin_amdgcn_sqrtf(1.0f - a) * p;
    return (d >= 0.0f) ? r : (PI_F - r);
}

// Lane pair (r, r+32) shares one query row: half h = lane>>5 owns joints
// h*11 .. h*11+10 (h=1's 11th is a clamped dummy, masked out of the sum).
// Per-thread state: 11 query quats (44 VGPR) + 11-quat train buffer (44 VGPR)
// -> fits the 128-VGPR cap that amdgpu_waves_per_eu(4,4) pins, no spills.
__global__ __attribute__((amdgpu_flat_work_group_size(TPB, TPB)))
__attribute__((amdgpu_waves_per_eu(4, 4)))
void pose_dist_kernel(const float* __restrict__ pose,
                      const float* __restrict__ train,
                      float* __restrict__ ws,
                      int chunks, int mchunk) {
    const int nb   = blockIdx.x / chunks;   // query group (0..31)
    const int cb   = blockIdx.x % chunks;   // m-chunk
    const int lane = threadIdx.x;
    const int h    = lane >> 5;
    const int n    = nb * 32 + (lane & 31); // query row for this lane pair
    const int jbase = h * JH;               // 0 or 11

    float4 q[JH];
    const float4* __restrict__ pp = (const float4*)(pose + (size_t)n * NJOINT * 4);
#pragma unroll
    for (int jj = 0; jj < JH; ++jj) {
        int jg = jbase + jj; if (jg > NJOINT - 1) jg = NJOINT - 1;  // clamp dummy
        float4 v = pp[jg];
        float inv = rsqrtf(v.x * v.x + v.y * v.y + v.z * v.z + v.w * v.w);
        v.x *= inv; v.y *= inv; v.z *= inv; v.w *= inv;
        q[jj] = v;
    }

    float t0 = BIGF, t1 = BIGF, t2 = BIGF, t3 = BIGF, t4 = BIGF;
    const float4* __restrict__ tq =
        (const float4*)train + (size_t)cb * mchunk * NJOINT + jbase;

    for (int mi = 0; mi < mchunk; ++mi) {
        const float4* __restrict__ tm = tq + (size_t)mi * NJOINT;
        float4 buf[JH];
#pragma unroll
        for (int jj = 0; jj < JH; ++jj) {
            int o = jj; if (jbase + jj > NJOINT - 1) o = jj - 1;   // dummy re-reads j20
            buf[jj] = tm[o];
        }
        float a0 = 0.f, a1 = 0.f;
#pragma unroll
        for (int jj = 0; jj < JH; ++jj) {
            float4 p = q[jj], u = buf[jj];
            float d = u.x * p.x + u.y * p.y + u.z * p.z + u.w * p.w;
            float rr = acos_fast(d);
            if (jj == JH - 1) rr = h ? 0.f : rr;   // mask the dummy joint
            if (jj & 1) a1 += rr; else a0 += rr;
        }
        float acc  = a0 + a1;
        float v = (acc + __shfl_xor(acc, 32)) * 0.5f;
        // branchless sorted insert (ascending top-5), identical on both halves
        t4 = fminf(t4, fmaxf(t3, v));
        t3 = fminf(t3, fmaxf(t2, v));
        t2 = fminf(t2, fmaxf(t1, v));
        t1 = fminf(t1, fmaxf(t0, v));
        t0 = fminf(t0, v);
    }

    if (lane < 32) {
        float* w = ws + ((size_t)n * chunks + cb) * KNEIGH;
        w[0] = t0; w[1] = t1; w[2] = t2; w[3] = t3; w[4] = t4;
    }
}

// one wave per query row: merge chunks*5 candidates -> mean of top-5
__global__ __launch_bounds__(64)
void pose_reduce_kernel(const float* __restrict__ ws, float* __restrict__ out,
                        int chunks) {
    const int n = blockIdx.x;
    const int lane = threadIdx.x;
    const int total = chunks * KNEIGH;
    const float* __restrict__ w = ws + (size_t)n * total;

    float t0 = BIGF, t1 = BIGF, t2 = BIGF, t3 = BIGF, t4 = BIGF;
    for (int i = lane; i < total; i += 64) {
        float v = w[i];
        t4 = fminf(t4, fmaxf(t3, v));
        t3 = fminf(t3, fmaxf(t2, v));
        t2 = fminf(t2, fmaxf(t1, v));
        t1 = fminf(t1, fmaxf(t0, v));
        t0 = fminf(t0, v);
    }

    float sum = 0.f;
#pragma unroll
    for (int r = 0; r < KNEIGH; ++r) {
        float v = t0; int who = lane;
        for (int off = 32; off; off >>= 1) {
            float ov = __shfl_xor(v, off);
            int   ow = __shfl_xor(who, off);
            if (ov < v || (ov == v && ow < who)) { v = ov; who = ow; }
        }
        sum += v;
        if (lane == who) { t0 = t1; t1 = t2; t2 = t3; t3 = t4; t4 = BIGF; }
    }
    if (lane == 0) out[n] = sum * (1.0f / KNEIGH);
}

extern "C" void kernel_launch(void* const* d_in, const int* in_sizes, int n_in,
                              void* d_out, int out_size, void* d_ws, size_t ws_size,
                              hipStream_t stream) {
    const float* pose  = (const float*)d_in[0];
    const float* train = (const float*)d_in[1];
    float* out = (float*)d_out;
    float* ws  = (float*)d_ws;

    // 32 n-groups x 125 chunks = 4000 waves ~= 4/SIMD, matching waves_per_eu(4,4)
    int chunks = 125;
    if ((size_t)N_POSE * chunks * KNEIGH * sizeof(float) > ws_size) chunks = 50;
    if ((size_t)N_POSE * chunks * KNEIGH * sizeof(float) > ws_size) chunks = 10;
    const int mchunk = M_TRAIN / chunks;

    dim3 grid1((N_POSE / 32) * chunks);
    pose_dist_kernel<<<grid1, TPB, 0, stream>>>(pose, train, ws, chunks, mchunk);

    pose_reduce_kernel<<<dim3(N_POSE), dim3(64), 0, stream>>>(ws, out, chunks);
}

// Round 5
// 137.926 us; speedup vs baseline: 1.0473x; 1.0473x over previous
//
#include <hip/hip_runtime.h>
#include <math.h>

#define N_POSE   1024
#define M_TRAIN  10000
#define NJOINT   21
#define KNEIGH   5
#define CLIPV    (1.0f - 1e-7f)
#define PI_F     3.14159265358979f
#define BIGF     1e30f
#define MB       8                      // train poses per register block
#define QN_FLOATS (N_POSE * NJOINT * 4) // normalized-pose staging in ws

// A&S 4.4.45 poly (abs err ~1.8e-4) with raw v_sqrt_f32 (no ocml fixup code)
__device__ __forceinline__ float acos_fast(float d) {
    float a = fminf(fabsf(d), CLIPV);
    float p = fmaf(a, -0.0187293f, 0.0742610f);
    p = fmaf(a, p, -0.2121144f);
    p = fmaf(a, p, 1.5707288f);
    float r = __builtin_amdgcn_sqrtf(1.0f - a) * p;
    return (d >= 0.0f) ? r : (PI_F - r);
}

// one-shot: normalize all query quats into ws so the hot loop has no rsqrt
__global__ __launch_bounds__(256)
void pose_norm_kernel(const float* __restrict__ pose, float* __restrict__ qn) {
    int i = blockIdx.x * blockDim.x + threadIdx.x;   // global quat index
    if (i >= N_POSE * NJOINT) return;
    float4 v = ((const float4*)pose)[i];
    float inv = rsqrtf(v.x * v.x + v.y * v.y + v.z * v.z + v.w * v.w);
    v.x *= inv; v.y *= inv; v.z *= inv; v.w *= inv;
    ((float4*)qn)[i] = v;
}

// thread = query row; MB train poses held as accumulator block; ONE query quat
// resident at a time (4 VGPR + 4 prefetch) -> ~41 live VGPRs, spill-free by
// construction. Train addresses are wave-uniform -> s_load into SGPRs.
__global__ __launch_bounds__(64)
void pose_dist_kernel(const float* __restrict__ qn,
                      const float* __restrict__ train,
                      float* __restrict__ topk,
                      int chunks, int mchunk) {
    const int nb = blockIdx.x / chunks;   // query group (0..15)
    const int cb = blockIdx.x % chunks;   // m-chunk
    const int n  = nb * 64 + threadIdx.x;

    const float4* __restrict__ qp = (const float4*)qn + (size_t)n * NJOINT;
    const float4* __restrict__ tq = (const float4*)train + (size_t)cb * mchunk * NJOINT;

    float t0 = BIGF, t1 = BIGF, t2 = BIGF, t3 = BIGF, t4 = BIGF;

#pragma unroll 1
    for (int mb = 0; mb < mchunk; mb += MB) {
        const float4* __restrict__ tb = tq + (size_t)mb * NJOINT;
        float acc[MB];
#pragma unroll
        for (int k = 0; k < MB; ++k) acc[k] = 0.f;

        float4 qc = qp[0];
#pragma unroll 1
        for (int j = 0; j < NJOINT; ++j) {
            float4 qnx = qp[(j + 1 < NJOINT) ? j + 1 : 0];  // prefetch next joint
#pragma unroll
            for (int mm = 0; mm < MB; ++mm) {
                float4 u = tb[(size_t)mm * NJOINT + j];     // wave-uniform
                float d = u.x * qc.x + u.y * qc.y + u.z * qc.z + u.w * qc.w;
                acc[mm] += acos_fast(d);
            }
            qc = qnx;
        }
#pragma unroll
        for (int mm = 0; mm < MB; ++mm) {
            float v = acc[mm] * 0.5f;
            t4 = fminf(t4, fmaxf(t3, v));
            t3 = fminf(t3, fmaxf(t2, v));
            t2 = fminf(t2, fmaxf(t1, v));
            t1 = fminf(t1, fmaxf(t0, v));
            t0 = fminf(t0, v);
        }
    }

    float* w = topk + ((size_t)n * chunks + cb) * KNEIGH;
    w[0] = t0; w[1] = t1; w[2] = t2; w[3] = t3; w[4] = t4;
}

// one wave per query row: merge chunks*5 candidates -> mean of top-5
__global__ __launch_bounds__(64)
void pose_reduce_kernel(const float* __restrict__ topk, float* __restrict__ out,
                        int chunks) {
    const int n = blockIdx.x;
    const int lane = threadIdx.x;
    const int total = chunks * KNEIGH;
    const float* __restrict__ w = topk + (size_t)n * total;

    float t0 = BIGF, t1 = BIGF, t2 = BIGF, t3 = BIGF, t4 = BIGF;
    for (int i = lane; i < total; i += 64) {
        float v = w[i];
        t4 = fminf(t4, fmaxf(t3, v));
        t3 = fminf(t3, fmaxf(t2, v));
        t2 = fminf(t2, fmaxf(t1, v));
        t1 = fminf(t1, fmaxf(t0, v));
        t0 = fminf(t0, v);
    }

    float sum = 0.f;
#pragma unroll
    for (int r = 0; r < KNEIGH; ++r) {
        float v = t0; int who = lane;
        for (int off = 32; off; off >>= 1) {
            float ov = __shfl_xor(v, off);
            int   ow = __shfl_xor(who, off);
            if (ov < v || (ov == v && ow < who)) { v = ov; who = ow; }
        }
        sum += v;
        if (lane == who) { t0 = t1; t1 = t2; t2 = t3; t3 = t4; t4 = BIGF; }
    }
    if (lane == 0) out[n] = sum * (1.0f / KNEIGH);
}

extern "C" void kernel_launch(void* const* d_in, const int* in_sizes, int n_in,
                              void* d_out, int out_size, void* d_ws, size_t ws_size,
                              hipStream_t stream) {
    const float* pose  = (const float*)d_in[0];
    const float* train = (const float*)d_in[1];
    float* out  = (float*)d_out;
    float* qn   = (float*)d_ws;                 // QN_FLOATS floats
    float* topk = (float*)d_ws + QN_FLOATS;

    // largest chunk tier whose topk area fits ws (tiers divide 10000; mchunk % 8 == 0)
    size_t base = (size_t)QN_FLOATS * sizeof(float);
    int chunks = 250;
    if (base + (size_t)N_POSE * chunks * KNEIGH * sizeof(float) > ws_size) chunks = 125;
    if (base + (size_t)N_POSE * chunks * KNEIGH * sizeof(float) > ws_size) chunks = 50;
    if (base + (size_t)N_POSE * chunks * KNEIGH * sizeof(float) > ws_size) chunks = 10;
    const int mchunk = M_TRAIN / chunks;

    pose_norm_kernel<<<dim3((N_POSE * NJOINT + 255) / 256), dim3(256), 0, stream>>>(pose, qn);

    dim3 grid1((N_POSE / 64) * chunks);
    pose_dist_kernel<<<grid1, dim3(64), 0, stream>>>(qn, train, topk, chunks, mchunk);

    pose_reduce_kernel<<<dim3(N_POSE), dim3(64), 0, stream>>>(topk, out, chunks);
}